// Round 7
// baseline (322.668 us; speedup 1.0000x reference)
//
#include <hip/hip_runtime.h>

// Complex MHA, B=4 S=1024 E=1024 H=16 DH=64.
// pack(fp32->fp16, K-concat complex trick) -> GEMM1 (256x128x32, 3-buffer
// counted-vmcnt pipeline, 32x32 MFMA, scatter epilogue) -> flash complex
// attention (swapped-operand 32x32) -> GEMM2 (same gemm template).

typedef _Float16 f16;
typedef _Float16 f16x8 __attribute__((ext_vector_type(8)));
typedef _Float16 f16x4 __attribute__((ext_vector_type(4)));
typedef float f32x4 __attribute__((ext_vector_type(4)));
typedef float f32x16 __attribute__((ext_vector_type(16)));

#define MFMA16(a, b, c) __builtin_amdgcn_mfma_f32_16x16x32_f16(a, b, c, 0, 0, 0)
#define MFMA32(a, b, c) __builtin_amdgcn_mfma_f32_32x32x16_f16(a, b, c, 0, 0, 0)

__device__ inline void load_lds16(const void* g, void* l) {
  __builtin_amdgcn_global_load_lds(
      (const __attribute__((address_space(1))) unsigned int*)g,
      (__attribute__((address_space(3))) unsigned int*)l, 16, 0, 0);
}

__device__ inline unsigned pkrtz(float a, float b) {
  auto t = __builtin_amdgcn_cvt_pkrtz(a, b);
  return __builtin_bit_cast(unsigned, t);
}

// ---------------- pack kernels (fp32 -> fp16, concat layouts) ----------------

__global__ void pack_x_kernel(const float* __restrict__ xr, const float* __restrict__ xi,
                              f16* __restrict__ XC) {
  int i = blockIdx.x * 256 + threadIdx.x;
  if (i >= (4096 * 2048 / 4)) return;
  int idx = i * 4;
  int m = idx >> 11, k = idx & 2047;
  const float* src = (k < 1024) ? (xr + (size_t)m * 1024 + k) : (xi + (size_t)m * 1024 + k - 1024);
  float4 v = *(const float4*)src;
  f16x4 o = {(f16)v.x, (f16)v.y, (f16)v.z, (f16)v.w};
  *(f16x4*)(XC + idx) = o;
}

__global__ void pack_wqkv_kernel(const float* __restrict__ wr, const float* __restrict__ wi,
                                 f16* __restrict__ W) {
  int i = blockIdx.x * 256 + threadIdx.x;
  if (i >= (6144 * 2048 / 4)) return;
  int idx = i * 4;
  int n = idx >> 11, k = idx & 2047;
  const float* base;
  float sgn = 1.f;
  if (n < 3072) {
    if (k < 1024) base = wr + (size_t)n * 1024 + k;
    else { base = wi + (size_t)n * 1024 + k - 1024; sgn = -1.f; }
  } else {
    int n2 = n - 3072;
    if (k < 1024) base = wi + (size_t)n2 * 1024 + k;
    else base = wr + (size_t)n2 * 1024 + k - 1024;
  }
  float4 v = *(const float4*)base;
  f16x4 o = {(f16)(sgn * v.x), (f16)(sgn * v.y), (f16)(sgn * v.z), (f16)(sgn * v.w)};
  *(f16x4*)(W + idx) = o;
}

__global__ void pack_wout_kernel(const float* __restrict__ wor, const float* __restrict__ woi,
                                 f16* __restrict__ W) {
  int i = blockIdx.x * 256 + threadIdx.x;
  if (i >= (2048 * 2048 / 4)) return;
  int idx = i * 4;
  int n = idx >> 11, k = idx & 2047;
  const float* base;
  float sgn = 1.f;
  if (n < 1024) {
    if (k < 1024) base = wor + (size_t)n * 1024 + k;
    else { base = woi + (size_t)n * 1024 + k - 1024; sgn = -1.f; }
  } else {
    int n2 = n - 1024;
    if (k < 1024) base = woi + (size_t)n2 * 1024 + k;
    else base = wor + (size_t)n2 * 1024 + k - 1024;
  }
  float4 v = *(const float4*)base;
  f16x4 o = {(f16)(sgn * v.x), (f16)(sgn * v.y), (f16)(sgn * v.z), (f16)(sgn * v.w)};
  *(f16x4*)(W + idx) = o;
}

struct GemmParams {
  f16 *QC, *KCr, *KCi, *VCT;
  const float *bpr, *bpi;
  float* out;
  const float *bor, *boi;
  int out_complex;
};

// ---------------- GEMM: BM=256 BN=128 BK=32, 3-buf counted pipeline ----------
// 256 threads / 4 waves (2M x 2N), wave tile 128x64, 32x32x16 MFMA.
// C[M, N] = A[M,2048] * B[N,2048]^T.

template <int MODE>
__global__ __launch_bounds__(256, 2) void gemm_kernel(const f16* __restrict__ A,
                                                      const f16* __restrict__ B,
                                                      GemmParams p, int ntPerXcd) {
  const int K = 2048;
  __shared__ alignas(16) f16 sA[3][128 * 64];  // 256 rows x 32 f16 (phys [128][64])
  __shared__ alignas(16) f16 sB[3][64 * 64];   // 128 rows x 32 f16
  const int tid = threadIdx.x;
  const int w = tid >> 6, l = tid & 63;
  const int lq = l & 31, hi = l >> 5;
  // XCD-chunked mapping, n-fastest within XCD (A-tile L2 reuse)
  const int lin = blockIdx.x;
  const int xcd = lin & 7, idx = lin >> 3;
  const int mt = idx / ntPerXcd, ntl = idx % ntPerXcd;
  const int tm0 = mt * 256;
  const int tn0 = (xcd * ntPerXcd + ntl) * 128;
  const int wm = (w >> 1) * 128, wn = (w & 1) * 64;

  // staging source (inverse-swizzled), linear LDS dest
  const int prow0 = tid >> 3, pch0 = tid & 7;
  const int lc0 = pch0 ^ (prow0 & 7);
  const int rA = prow0 * 2 + (lc0 >> 2), cA = lc0 & 3;
  const f16* gA = A + (size_t)(tm0 + rA) * K + cA * 8;
  const f16* gB = B + (size_t)(tn0 + rA) * K + cA * 8;
  const int wlds = w * 512;

#define STG_A(bi, k0)                                                 \
  do {                                                                \
    load_lds16(gA + (k0), &sA[bi][wlds]);                             \
    load_lds16(gA + (size_t)64 * K + (k0), &sA[bi][2048 + wlds]);     \
    load_lds16(gA + (size_t)128 * K + (k0), &sA[bi][4096 + wlds]);    \
    load_lds16(gA + (size_t)192 * K + (k0), &sA[bi][6144 + wlds]);    \
  } while (0)
#define STG_B(bi, k0)                                                 \
  do {                                                                \
    load_lds16(gB + (k0), &sB[bi][wlds]);                             \
    load_lds16(gB + (size_t)64 * K + (k0), &sB[bi][2048 + wlds]);     \
  } while (0)

  f32x16 acc[4][2] = {};

  // prologue: stage T0, T1; wait T0 (6 of T1 in flight)
  STG_A(0, 0);
  STG_B(0, 0);
  STG_A(1, 32);
  STG_B(1, 32);
  asm volatile("s_waitcnt vmcnt(6)" ::: "memory");
  __builtin_amdgcn_s_barrier();

  int rd = 0, st = 2;
  for (int t = 0; t < 64; ++t) {
    const f16* pA = &sA[rd][0];
    const f16* pB = &sB[rd][0];
    const bool doStage = (t < 62);
    const int k2 = (t + 2) * 32;

    auto rdA = [&](int mi, int ks) -> f16x8 {
      int row = wm + mi * 32 + lq;
      int c8 = (((row & 1) << 2) + ks * 2 + hi) ^ ((row >> 1) & 7);
      return *(const f16x8*)&pA[(row >> 1) * 64 + c8 * 8];
    };
    auto rdB = [&](int nj, int ks) -> f16x8 {
      int row = wn + nj * 32 + lq;
      int c8 = (((row & 1) << 2) + ks * 2 + hi) ^ ((row >> 1) & 7);
      return *(const f16x8*)&pB[(row >> 1) * 64 + c8 * 8];
    };

    // ---- phase 0: read A0-1/B0-1 | stage A(t+2) | 8 MFMA ----
    f16x8 af[2][2], bf[2][2];
#pragma unroll
    for (int mi = 0; mi < 2; ++mi)
#pragma unroll
      for (int ks = 0; ks < 2; ++ks) af[mi][ks] = rdA(mi, ks);
#pragma unroll
    for (int nj = 0; nj < 2; ++nj)
#pragma unroll
      for (int ks = 0; ks < 2; ++ks) bf[nj][ks] = rdB(nj, ks);
    if (doStage) STG_A(st, k2);
    __builtin_amdgcn_s_barrier();
    asm volatile("s_waitcnt lgkmcnt(0)" ::: "memory");
    __builtin_amdgcn_sched_barrier(0);
    __builtin_amdgcn_s_setprio(1);
#pragma unroll
    for (int mi = 0; mi < 2; ++mi)
#pragma unroll
      for (int nj = 0; nj < 2; ++nj) {
        acc[mi][nj] = MFMA32(af[mi][0], bf[nj][0], acc[mi][nj]);
        acc[mi][nj] = MFMA32(af[mi][1], bf[nj][1], acc[mi][nj]);
      }
    __builtin_amdgcn_s_setprio(0);
    __builtin_amdgcn_s_barrier();

    // ---- phase 1: read A2-3 | stage B(t+2) | 8 MFMA | counted vmcnt ----
    f16x8 af2[2][2];
#pragma unroll
    for (int mi = 0; mi < 2; ++mi)
#pragma unroll
      for (int ks = 0; ks < 2; ++ks) af2[mi][ks] = rdA(2 + mi, ks);
    if (doStage) STG_B(st, k2);
    __builtin_amdgcn_s_barrier();
    asm volatile("s_waitcnt lgkmcnt(0)" ::: "memory");
    __builtin_amdgcn_sched_barrier(0);
    __builtin_amdgcn_s_setprio(1);
#pragma unroll
    for (int mi = 0; mi < 2; ++mi)
#pragma unroll
      for (int nj = 0; nj < 2; ++nj) {
        acc[2 + mi][nj] = MFMA32(af2[mi][0], bf[nj][0], acc[2 + mi][nj]);
        acc[2 + mi][nj] = MFMA32(af2[mi][1], bf[nj][1], acc[2 + mi][nj]);
      }
    __builtin_amdgcn_s_setprio(0);
    if (doStage) asm volatile("s_waitcnt vmcnt(6)" ::: "memory");
    else asm volatile("s_waitcnt vmcnt(0)" ::: "memory");
    __builtin_amdgcn_s_barrier();

    rd = (rd == 2) ? 0 : rd + 1;
    st = (st == 2) ? 0 : st + 1;
  }
#undef STG_A
#undef STG_B

  // ---- epilogue: C/D 32x32 layout col=lane&31, row=(r&3)+8*(r>>2)+4*hi ----
#pragma unroll
  for (int mi = 0; mi < 4; ++mi)
#pragma unroll
    for (int nj = 0; nj < 2; ++nj) {
      int n = tn0 + wn + nj * 32 + lq;
      if constexpr (MODE == 0) {
        bool im = n >= 3072;
        int nn = im ? n - 3072 : n;
        float bias = im ? p.bpi[nn] : p.bpr[nn];
        int part = nn >> 10;
        int e = nn & 1023, h = e >> 6, d = e & 63;
#pragma unroll
        for (int g = 0; g < 4; ++g) {
          int m0 = tm0 + wm + mi * 32 + g * 8 + hi * 4;
          int bb = m0 >> 10, s0 = m0 & 1023;
          size_t bh = (size_t)bb * 16 + h;
          if (part == 0) {
#pragma unroll
            for (int j = 0; j < 4; ++j)
              p.QC[(bh * 1024 + s0 + j) * 128 + (im ? 64 : 0) + d] =
                  (f16)((acc[mi][nj][g * 4 + j] + bias) * 0.125f);
          } else if (part == 1) {
#pragma unroll
            for (int j = 0; j < 4; ++j) {
              float v2 = acc[mi][nj][g * 4 + j] + bias;
              size_t o = (bh * 1024 + s0 + j) * 128;
              if (!im) { p.KCr[o + d] = (f16)v2; p.KCi[o + 64 + d] = (f16)v2; }
              else     { p.KCr[o + 64 + d] = (f16)(-v2); p.KCi[o + d] = (f16)v2; }
            }
          } else {
            f16x4 vv;
#pragma unroll
            for (int j = 0; j < 4; ++j) vv[j] = (f16)(acc[mi][nj][g * 4 + j] + bias);
            *(f16x4*)&p.VCT[((bh * 128 + (im ? 64 : 0) + d)) * 1024 + s0] = vv;
          }
        }
      } else {
#pragma unroll
        for (int g = 0; g < 4; ++g) {
          int m0 = tm0 + wm + mi * 32 + g * 8 + hi * 4;
#pragma unroll
          for (int j = 0; j < 4; ++j) {
            float val = acc[mi][nj][g * 4 + j];
            size_t m = (size_t)(m0 + j);
            if (n < 1024) {
              float v2 = val + p.bor[n];
              if (p.out_complex) p.out[(m * 1024 + n) * 2] = v2;
              else p.out[m * 1024 + n] = v2;
            } else {
              if (p.out_complex) p.out[(m * 1024 + n - 1024) * 2 + 1] = val + p.boi[n - 1024];
            }
          }
        }
      }
    }
}

// ---------------- flash complex attention (swapped-operand 32x32) -------------

__global__ __launch_bounds__(512, 2) void attn_kernel(const f16* __restrict__ QC,
                                                      const f16* __restrict__ KCr,
                                                      const f16* __restrict__ KCi,
                                                      const f16* __restrict__ VCT,
                                                      f16* __restrict__ OC) {
  __shared__ alignas(16) f16 sKr[2][32 * 128];
  __shared__ alignas(16) f16 sKi[2][32 * 128];
  __shared__ alignas(16) f16 sV[2][128 * 32];
  const int tid = threadIdx.x;
  const int w = tid >> 6, l = tid & 63;
  const int lq = l & 31, hi = l >> 5;
  const int bid = blockIdx.x;
  const int xx = bid & 7, yy = bid >> 3;
  const int bh = xx + ((yy >> 2) << 3);
  const int qt = yy & 3;
  const int q0 = qt * 256 + w * 32;
  const f16* Qb = QC + (size_t)bh * 1024 * 128;
  const f16* Krb = KCr + (size_t)bh * 1024 * 128;
  const f16* Kib = KCi + (size_t)bh * 1024 * 128;
  const f16* Vb = VCT + (size_t)bh * 128 * 1024;

  f16x8 qf[8];
#pragma unroll
  for (int c = 0; c < 8; ++c)
    qf[c] = *(const f16x8*)&Qb[(size_t)(q0 + lq) * 128 + c * 16 + hi * 8];

  f32x16 accR[4] = {};
  f32x16 accI[4] = {};
  float m_r = -1e30f, l_r = 0.f, m_i = -1e30f, l_i = 0.f;

  const int sprow = tid >> 3;
  const int cK = (tid & 7) ^ ((tid >> 4) & 7);
  const f16* gKr = Krb + (size_t)(tid >> 4) * 128 + ((tid >> 3) & 1) * 64 + cK * 8;
  const f16* gKi = Kib + (size_t)(tid >> 4) * 128 + ((tid >> 3) & 1) * 64 + cK * 8;
  const int cV = (tid & 7) ^ (sprow & 7);
  const f16* gV = Vb + (size_t)(sprow * 2 + (cV >> 2)) * 1024 + (cV & 3) * 8;
  const int ldsW = w * 512;

#define STAGE(s, k0)                                                 \
  do {                                                               \
    load_lds16(gKr + (size_t)(k0) * 128, &sKr[s][ldsW]);             \
    load_lds16(gKi + (size_t)(k0) * 128, &sKi[s][ldsW]);             \
    load_lds16(gV + (k0), &sV[s][ldsW]);                             \
  } while (0)

  STAGE(0, 0);
  asm volatile("s_waitcnt vmcnt(0)" ::: "memory");
  __syncthreads();
  int cur = 0;

  for (int t = 0; t < 32; ++t) {
    if (t < 31) STAGE(cur ^ 1, (t + 1) * 32);

    f32x16 sr = {}, si = {};
    __builtin_amdgcn_s_setprio(1);
#pragma unroll
    for (int c = 0; c < 8; ++c) {
      int fc = c * 2 + hi;
      int prow = lq * 2 + (fc >> 3);
      int swzc = (fc & 7) ^ (lq & 7);
      f16x8 kr = *(const f16x8*)&sKr[cur][prow * 64 + swzc * 8];
      f16x8 ki = *(const f16x8*)&sKi[cur][prow * 64 + swzc * 8];
      sr = MFMA32(kr, qf[c], sr);
      si = MFMA32(ki, qf[c], si);
    }
    __builtin_amdgcn_s_setprio(0);

    f16x8 prf[2], pif[2];
#pragma unroll
    for (int part = 0; part < 2; ++part) {
      const f32x16& s = part ? si : sr;
      float& m = part ? m_i : m_r;
      float& lsum = part ? l_i : l_r;
      f32x16* acc = part ? accI : accR;
      float vm = s[0];
#pragma unroll
      for (int j = 1; j < 16; ++j) vm = fmaxf(vm, s[j]);
      vm = fmaxf(vm, __shfl_xor(vm, 32));
      if (__any(vm > m + 8.f)) {
        float mn = fmaxf(m, vm);
        float sc = __expf(m - mn);
        lsum *= sc;
#pragma unroll
        for (int a = 0; a < 4; ++a)
#pragma unroll
          for (int j = 0; j < 16; ++j) acc[a][j] *= sc;
        m = mn;
      }
      float p[16];
      float ls = 0.f;
#pragma unroll
      for (int j = 0; j < 16; ++j) { p[j] = __expf(s[j] - m); ls += p[j]; }
      lsum += ls;
      unsigned a0 = pkrtz(p[0], p[1]), b0 = pkrtz(p[4], p[5]);
      unsigned a1 = pkrtz(p[2], p[3]), b1 = pkrtz(p[6], p[7]);
      unsigned a2 = pkrtz(p[8], p[9]), b2 = pkrtz(p[12], p[13]);
      unsigned a3 = pkrtz(p[10], p[11]), b3 = pkrtz(p[14], p[15]);
      asm("v_permlane32_swap_b32 %0, %1" : "+v"(a0), "+v"(b0));
      asm("v_permlane32_swap_b32 %0, %1" : "+v"(a1), "+v"(b1));
      asm("v_permlane32_swap_b32 %0, %1" : "+v"(a2), "+v"(b2));
      asm("v_permlane32_swap_b32 %0, %1" : "+v"(a3), "+v"(b3));
      union { unsigned u[4]; f16x8 v; } f0, f1;
      f0.u[0] = a0; f0.u[1] = a1; f0.u[2] = b0; f0.u[3] = b1;
      f1.u[0] = a2; f1.u[1] = a3; f1.u[2] = b2; f1.u[3] = b3;
      if (part) { pif[0] = f0.v; pif[1] = f1.v; }
      else      { prf[0] = f0.v; prf[1] = f1.v; }
    }

    __builtin_amdgcn_s_setprio(1);
#pragma unroll
    for (int ft = 0; ft < 4; ++ft) {
#pragma unroll
      for (int ks = 0; ks < 2; ++ks) {
        int feat = ft * 32 + lq;
        int prow = feat >> 1;
        int swzc = (((feat & 1) * 4 + ks * 2 + hi) ^ (prow & 7));
        f16x8 vf = *(const f16x8*)&sV[cur][prow * 64 + swzc * 8];
        accR[ft] = MFMA32(vf, prf[ks], accR[ft]);
        accI[ft] = MFMA32(vf, pif[ks], accI[ft]);
      }
    }
    __builtin_amdgcn_s_setprio(0);

    asm volatile("s_waitcnt vmcnt(0)" ::: "memory");
    __syncthreads();
    cur ^= 1;
  }
#undef STAGE

  float lr = l_r + __shfl_xor(l_r, 32);
  float li = l_i + __shfl_xor(l_i, 32);
  float ilr = 1.f / lr, ili = 1.f / li;
  const int bb = bh >> 4, h = bh & 15;
  const int q = q0 + lq;
  f16* rowp = OC + ((size_t)bb * 1024 + q) * 2048 + h * 64;
#pragma unroll
  for (int tt = 0; tt < 2; ++tt) {
#pragma unroll
    for (int g = 0; g < 4; ++g) {
      int d0 = tt * 32 + g * 8 + hi * 4;
      f16x4 ov, oiv;
#pragma unroll
      for (int j = 0; j < 4; ++j) {
        int rg = g * 4 + j;
        float orv = accR[tt][rg] * ilr - accI[tt + 2][rg] * ili;
        float oivv = accR[tt + 2][rg] * ilr + accI[tt][rg] * ili;
        ov[j] = (f16)orv;
        oiv[j] = (f16)oivv;
      }
      *(f16x4*)(rowp + d0) = ov;
      *(f16x4*)(rowp + 1024 + d0) = oiv;
    }
  }
}

// ---------------- launcher ----------------------------------------------------

extern "C" void kernel_launch(void* const* d_in, const int* in_sizes, int n_in,
                              void* d_out, int out_size, void* d_ws, size_t ws_size,
                              hipStream_t stream) {
  const float* xr = (const float*)d_in[0];
  const float* xi = (const float*)d_in[1];
  const float* wpr = (const float*)d_in[2];
  const float* wpi = (const float*)d_in[3];
  const float* bpr = (const float*)d_in[4];
  const float* bpi = (const float*)d_in[5];
  const float* wor = (const float*)d_in[6];
  const float* woi = (const float*)d_in[7];
  const float* bor = (const float*)d_in[8];
  const float* boi = (const float*)d_in[9];

  f16* ws = (f16*)d_ws;
  f16* XC = ws;                       // 4096*2048
  f16* WQKV = XC + 8388608;           // 6144*2048
  f16* QC = WQKV + 12582912;          // 64*1024*128
  f16* KCr = QC + 8388608;
  f16* KCi = KCr + 8388608;
  f16* VCT = KCi + 8388608;           // 64*128*1024
  f16* OC = VCT + 8388608;            // 4096*2048
  f16* WOUT = OC + 8388608;           // 2048*2048

  pack_x_kernel<<<8192, 256, 0, stream>>>(xr, xi, XC);
  pack_wqkv_kernel<<<12288, 256, 0, stream>>>(wpr, wpi, WQKV);
  pack_wout_kernel<<<4096, 256, 0, stream>>>(wor, woi, WOUT);

  GemmParams p1 = {};
  p1.QC = QC; p1.KCr = KCr; p1.KCi = KCi; p1.VCT = VCT;
  p1.bpr = bpr; p1.bpi = bpi;
  // M=4096 (16 m-tiles), N=6144 (48 n-tiles = 8 XCD x 6)
  gemm_kernel<0><<<768, 256, 0, stream>>>(XC, WQKV, p1, 6);

  attn_kernel<<<256, 512, 0, stream>>>(QC, KCr, KCi, VCT, OC);

  GemmParams p2 = {};
  p2.out = (float*)d_out; p2.bor = bor; p2.boi = boi;
  p2.out_complex = (out_size == 8388608) ? 1 : 0;
  int ntPer = p2.out_complex ? 2 : 1;  // N = 2048 or 1024
  gemm_kernel<1><<<8 * 16 * ntPer, 256, 0, stream>>>(OC, WOUT, p2, ntPer);
}

// Round 8
// 298.374 us; speedup vs baseline: 1.0814x; 1.0814x over previous
//
#include <hip/hip_runtime.h>

// Complex MHA, B=4 S=1024 E=1024 H=16 DH=64.
// pack(fp32->fp16, K-concat complex trick) -> GEMM1 (m201-style 256^2 BK=64
// 8-wave quadrant-phase pipeline, scatter epilogue) -> flash complex attention
// (swapped-operand 32x32) -> GEMM2 (m97 128^2).

typedef _Float16 f16;
typedef _Float16 f16x8 __attribute__((ext_vector_type(8)));
typedef _Float16 f16x4 __attribute__((ext_vector_type(4)));
typedef float f32x4 __attribute__((ext_vector_type(4)));
typedef float f32x16 __attribute__((ext_vector_type(16)));

#define MFMA16(a, b, c) __builtin_amdgcn_mfma_f32_16x16x32_f16(a, b, c, 0, 0, 0)
#define MFMA32(a, b, c) __builtin_amdgcn_mfma_f32_32x32x16_f16(a, b, c, 0, 0, 0)

__device__ inline void load_lds16(const void* g, void* l) {
  __builtin_amdgcn_global_load_lds(
      (const __attribute__((address_space(1))) unsigned int*)g,
      (__attribute__((address_space(3))) unsigned int*)l, 16, 0, 0);
}

__device__ inline unsigned pkrtz(float a, float b) {
  auto t = __builtin_amdgcn_cvt_pkrtz(a, b);
  return __builtin_bit_cast(unsigned, t);
}

// ---------------- pack kernels (fp32 -> fp16, concat layouts) ----------------

__global__ void pack_x_kernel(const float* __restrict__ xr, const float* __restrict__ xi,
                              f16* __restrict__ XC) {
  int i = blockIdx.x * 256 + threadIdx.x;
  if (i >= (4096 * 2048 / 4)) return;
  int idx = i * 4;
  int m = idx >> 11, k = idx & 2047;
  const float* src = (k < 1024) ? (xr + (size_t)m * 1024 + k) : (xi + (size_t)m * 1024 + k - 1024);
  float4 v = *(const float4*)src;
  f16x4 o = {(f16)v.x, (f16)v.y, (f16)v.z, (f16)v.w};
  *(f16x4*)(XC + idx) = o;
}

__global__ void pack_wqkv_kernel(const float* __restrict__ wr, const float* __restrict__ wi,
                                 f16* __restrict__ W) {
  int i = blockIdx.x * 256 + threadIdx.x;
  if (i >= (6144 * 2048 / 4)) return;
  int idx = i * 4;
  int n = idx >> 11, k = idx & 2047;
  const float* base;
  float sgn = 1.f;
  if (n < 3072) {
    if (k < 1024) base = wr + (size_t)n * 1024 + k;
    else { base = wi + (size_t)n * 1024 + k - 1024; sgn = -1.f; }
  } else {
    int n2 = n - 3072;
    if (k < 1024) base = wi + (size_t)n2 * 1024 + k;
    else base = wr + (size_t)n2 * 1024 + k - 1024;
  }
  float4 v = *(const float4*)base;
  f16x4 o = {(f16)(sgn * v.x), (f16)(sgn * v.y), (f16)(sgn * v.z), (f16)(sgn * v.w)};
  *(f16x4*)(W + idx) = o;
}

__global__ void pack_wout_kernel(const float* __restrict__ wor, const float* __restrict__ woi,
                                 f16* __restrict__ W) {
  int i = blockIdx.x * 256 + threadIdx.x;
  if (i >= (2048 * 2048 / 4)) return;
  int idx = i * 4;
  int n = idx >> 11, k = idx & 2047;
  const float* base;
  float sgn = 1.f;
  if (n < 1024) {
    if (k < 1024) base = wor + (size_t)n * 1024 + k;
    else { base = woi + (size_t)n * 1024 + k - 1024; sgn = -1.f; }
  } else {
    int n2 = n - 1024;
    if (k < 1024) base = woi + (size_t)n2 * 1024 + k;
    else base = wor + (size_t)n2 * 1024 + k - 1024;
  }
  float4 v = *(const float4*)base;
  f16x4 o = {(f16)(sgn * v.x), (f16)(sgn * v.y), (f16)(sgn * v.z), (f16)(sgn * v.w)};
  *(f16x4*)(W + idx) = o;
}

struct GemmParams {
  f16 *QC, *KCr, *KCi, *VCT;
  const float *bpr, *bpi;
  float* out;
  const float *bor, *boi;
  int out_complex;
};

// ---------------- GEMM1: 256^2 BK=64, 8 waves, quadrant phases ----------------
// C[4096, 6144] = A[4096,2048] * B[6144,2048]^T, scatter epilogue.

__global__ __launch_bounds__(512, 2) void gemm1_kernel(const f16* __restrict__ A,
                                                       const f16* __restrict__ B,
                                                       GemmParams p) {
  const int K = 2048;
  __shared__ alignas(16) f16 sA[2][256 * 64];
  __shared__ alignas(16) f16 sB[2][256 * 64];
  const int tid = threadIdx.x;
  const int w = tid >> 6, l = tid & 63;
  const int lr = l & 15, lk = l >> 4;
  // XCD-chunked: xcd owns 3 n-tiles x 16 m-tiles
  const int lin = blockIdx.x;
  const int xcd = lin & 7, idx = lin >> 3;
  const int mt = idx / 3, ntl = idx % 3;
  const int tm0 = mt * 256;
  const int tn0 = (xcd * 3 + ntl) * 256;
  const int wm = (w >> 2) * 128, wn = (w & 3) * 64;

  // staging: linear LDS dest (tid*16B per call), inverse-swizzled source chunk
  const int srow = tid >> 3;
  const int slc = (tid & 7) ^ (srow & 7);
  const f16* gA = A + (size_t)(tm0 + srow) * K + slc * 8;
  const f16* gB = B + (size_t)(tn0 + srow) * K + slc * 8;
  const int wl = w << 9;  // w*512 f16 (wave-uniform dest piece)

#define STG_A(dst, k0) do {                                        \
    load_lds16(gA + (k0), &sA[dst][wl]);                           \
    load_lds16(gA + (size_t)64 * K + (k0), &sA[dst][4096 + wl]);   \
    load_lds16(gA + (size_t)128 * K + (k0), &sA[dst][8192 + wl]);  \
    load_lds16(gA + (size_t)192 * K + (k0), &sA[dst][12288 + wl]); \
  } while (0)
#define STG_B(dst, k0) do {                                        \
    load_lds16(gB + (k0), &sB[dst][wl]);                           \
    load_lds16(gB + (size_t)64 * K + (k0), &sB[dst][4096 + wl]);   \
    load_lds16(gB + (size_t)128 * K + (k0), &sB[dst][8192 + wl]);  \
    load_lds16(gB + (size_t)192 * K + (k0), &sB[dst][12288 + wl]); \
  } while (0)

  f32x4 acc[8][4] = {};
  f16x8 af[4][2], bf[4][2];

  STG_A(0, 0);
  STG_B(0, 0);
  asm volatile("s_waitcnt vmcnt(0)" ::: "memory");
  __builtin_amdgcn_s_barrier();

  for (int t = 0; t < 32; ++t) {
    const int d = t & 1;
    const f16* pA = &sA[d][0];
    const f16* pB = &sB[d][0];
    const int kn = (t + 1) * 64;

    // ---- ph1: read af(mi0-3)+bf(nj0-1) | stage A(t+1) | MFMA Q00 (16) ----
#pragma unroll
    for (int mi = 0; mi < 4; ++mi) {
      int row = wm + mi * 16 + lr;
#pragma unroll
      for (int ks = 0; ks < 2; ++ks)
        af[mi][ks] = *(const f16x8*)&pA[row * 64 + (((ks * 4 + lk) ^ (row & 7)) * 8)];
    }
#pragma unroll
    for (int nj = 0; nj < 2; ++nj) {
      int row = wn + nj * 16 + lr;
#pragma unroll
      for (int ks = 0; ks < 2; ++ks)
        bf[nj][ks] = *(const f16x8*)&pB[row * 64 + (((ks * 4 + lk) ^ (row & 7)) * 8)];
    }
    if (t < 31) STG_A(d ^ 1, kn);
    __builtin_amdgcn_s_barrier();
    asm volatile("s_waitcnt lgkmcnt(0)" ::: "memory");
    __builtin_amdgcn_sched_barrier(0);
    __builtin_amdgcn_s_setprio(1);
#pragma unroll
    for (int mi = 0; mi < 4; ++mi)
#pragma unroll
      for (int nj = 0; nj < 2; ++nj) {
        acc[mi][nj] = MFMA16(af[mi][0], bf[nj][0], acc[mi][nj]);
        acc[mi][nj] = MFMA16(af[mi][1], bf[nj][1], acc[mi][nj]);
      }
    __builtin_amdgcn_s_setprio(0);
    __builtin_amdgcn_s_barrier();

    // ---- ph2: read bf(nj2-3) | stage B(t+1) | MFMA Q01 (16) ----
#pragma unroll
    for (int nj = 2; nj < 4; ++nj) {
      int row = wn + nj * 16 + lr;
#pragma unroll
      for (int ks = 0; ks < 2; ++ks)
        bf[nj][ks] = *(const f16x8*)&pB[row * 64 + (((ks * 4 + lk) ^ (row & 7)) * 8)];
    }
    if (t < 31) STG_B(d ^ 1, kn);
    __builtin_amdgcn_s_barrier();
    asm volatile("s_waitcnt lgkmcnt(0)" ::: "memory");
    __builtin_amdgcn_sched_barrier(0);
    __builtin_amdgcn_s_setprio(1);
#pragma unroll
    for (int mi = 0; mi < 4; ++mi)
#pragma unroll
      for (int nj = 2; nj < 4; ++nj) {
        acc[mi][nj] = MFMA16(af[mi][0], bf[nj][0], acc[mi][nj]);
        acc[mi][nj] = MFMA16(af[mi][1], bf[nj][1], acc[mi][nj]);
      }
    __builtin_amdgcn_s_setprio(0);
    __builtin_amdgcn_s_barrier();

    // ---- ph3+4: read af(mi4-7) | MFMA Q10+Q11 (32) | tile-end wait ----
#pragma unroll
    for (int mi = 0; mi < 4; ++mi) {
      int row = wm + (4 + mi) * 16 + lr;
#pragma unroll
      for (int ks = 0; ks < 2; ++ks)
        af[mi][ks] = *(const f16x8*)&pA[row * 64 + (((ks * 4 + lk) ^ (row & 7)) * 8)];
    }
    __builtin_amdgcn_s_barrier();
    asm volatile("s_waitcnt lgkmcnt(0)" ::: "memory");
    __builtin_amdgcn_sched_barrier(0);
    __builtin_amdgcn_s_setprio(1);
#pragma unroll
    for (int mi = 0; mi < 4; ++mi)
#pragma unroll
      for (int nj = 0; nj < 4; ++nj) {
        acc[4 + mi][nj] = MFMA16(af[mi][0], bf[nj][0], acc[4 + mi][nj]);
        acc[4 + mi][nj] = MFMA16(af[mi][1], bf[nj][1], acc[4 + mi][nj]);
      }
    __builtin_amdgcn_s_setprio(0);
    if (t < 31) asm volatile("s_waitcnt vmcnt(0)" ::: "memory");
    __builtin_amdgcn_s_barrier();
  }
#undef STG_A
#undef STG_B

  // ---- scatter epilogue (16x16 C/D: col=lane&15, row=lk*4+r) ----
#pragma unroll
  for (int mi = 0; mi < 8; ++mi)
#pragma unroll
    for (int nj = 0; nj < 4; ++nj) {
      int n = tn0 + wn + nj * 16 + lr;
      bool im = n >= 3072;
      int nn = im ? n - 3072 : n;
      float bias = im ? p.bpi[nn] : p.bpr[nn];
      int part = nn >> 10;
      int e = nn & 1023, h = e >> 6, dd = e & 63;
      int m0 = tm0 + wm + mi * 16 + lk * 4;
      int bb = m0 >> 10, s0 = m0 & 1023;
      size_t bh = (size_t)bb * 16 + h;
      if (part == 0) {
#pragma unroll
        for (int r = 0; r < 4; ++r)
          p.QC[(bh * 1024 + s0 + r) * 128 + (im ? 64 : 0) + dd] =
              (f16)((acc[mi][nj][r] + bias) * 0.125f);
      } else if (part == 1) {
#pragma unroll
        for (int r = 0; r < 4; ++r) {
          float v2 = acc[mi][nj][r] + bias;
          size_t o = (bh * 1024 + s0 + r) * 128;
          if (!im) { p.KCr[o + dd] = (f16)v2; p.KCi[o + 64 + dd] = (f16)v2; }
          else     { p.KCr[o + 64 + dd] = (f16)(-v2); p.KCi[o + dd] = (f16)v2; }
        }
      } else {
        f16x4 vv;
#pragma unroll
        for (int r = 0; r < 4; ++r) vv[r] = (f16)(acc[mi][nj][r] + bias);
        *(f16x4*)&p.VCT[((bh * 128 + (im ? 64 : 0) + dd)) * 1024 + s0] = vv;
      }
    }
}

// ---------------- GEMM2 (out proj): m97 128^2, proven 0-conflict --------------

__global__ __launch_bounds__(256) void gemm_out_kernel(const f16* __restrict__ A,
                                                       const f16* __restrict__ B,
                                                       GemmParams p) {
  const int K = 2048;
  __shared__ alignas(16) f16 sA[128 * 64];
  __shared__ alignas(16) f16 sB[128 * 64];
  const int tid = threadIdx.x;
  const int w = tid >> 6, l = tid & 63;
  const int lr = l & 15, lk = l >> 4;
  const int nwg = gridDim.x * gridDim.y;
  const int lin = blockIdx.y * gridDim.x + blockIdx.x;
  const int qq = nwg >> 3, rr = nwg & 7;
  const int xcd = lin & 7, off = lin >> 3;
  const int swz = (xcd < rr ? xcd * (qq + 1) : rr * (qq + 1) + (xcd - rr) * qq) + off;
  const int tm0 = (swz / gridDim.x) * 128;
  const int tn0 = (swz % gridDim.x) * 128;
  const int wm = (w >> 1) * 64, wn = (w & 1) * 64;

  f32x4 acc[4][4] = {};

  for (int k0 = 0; k0 < K; k0 += 64) {
#pragma unroll
    for (int i = 0; i < 4; ++i) {
      int slot = i * 256 + tid;
      int row = slot >> 3;
      int cg = (slot & 7) ^ (row & 7);
      load_lds16(A + (size_t)(tm0 + row) * K + k0 + cg * 8, &sA[(size_t)(i * 256 + (w << 6)) * 8]);
      load_lds16(B + (size_t)(tn0 + row) * K + k0 + cg * 8, &sB[(size_t)(i * 256 + (w << 6)) * 8]);
    }
    __syncthreads();
#pragma unroll
    for (int kk = 0; kk < 2; ++kk) {
      f16x8 af[4], bf[4];
#pragma unroll
      for (int t = 0; t < 4; ++t) {
        int rowA = wm + t * 16 + lr;
        af[t] = *(const f16x8*)&sA[rowA * 64 + ((kk * 4 + lk) ^ (rowA & 7)) * 8];
        int rowB = wn + t * 16 + lr;
        bf[t] = *(const f16x8*)&sB[rowB * 64 + ((kk * 4 + lk) ^ (rowB & 7)) * 8];
      }
#pragma unroll
      for (int mt = 0; mt < 4; ++mt)
#pragma unroll
        for (int nt = 0; nt < 4; ++nt) acc[mt][nt] = MFMA16(af[mt], bf[nt], acc[mt][nt]);
    }
    __syncthreads();
  }

#pragma unroll
  for (int mt = 0; mt < 4; ++mt)
#pragma unroll
    for (int nt = 0; nt < 4; ++nt)
#pragma unroll
      for (int r = 0; r < 4; ++r) {
        int m = tm0 + wm + mt * 16 + lk * 4 + r;
        int n = tn0 + wn + nt * 16 + lr;
        float val = acc[mt][nt][r];
        if (n < 1024) {
          float v2 = val + p.bor[n];
          if (p.out_complex) p.out[((size_t)m * 1024 + n) * 2] = v2;
          else p.out[(size_t)m * 1024 + n] = v2;
        } else {
          if (p.out_complex) p.out[((size_t)m * 1024 + n - 1024) * 2 + 1] = val + p.boi[n - 1024];
        }
      }
}

// ---------------- flash complex attention (swapped-operand 32x32) -------------

__global__ __launch_bounds__(512, 2) void attn_kernel(const f16* __restrict__ QC,
                                                      const f16* __restrict__ KCr,
                                                      const f16* __restrict__ KCi,
                                                      const f16* __restrict__ VCT,
                                                      f16* __restrict__ OC) {
  __shared__ alignas(16) f16 sKr[2][32 * 128];
  __shared__ alignas(16) f16 sKi[2][32 * 128];
  __shared__ alignas(16) f16 sV[2][128 * 32];
  const int tid = threadIdx.x;
  const int w = tid >> 6, l = tid & 63;
  const int lq = l & 31, hi = l >> 5;
  const int bid = blockIdx.x;
  const int xx = bid & 7, yy = bid >> 3;
  const int bh = xx + ((yy >> 2) << 3);
  const int qt = yy & 3;
  const int q0 = qt * 256 + w * 32;
  const f16* Qb = QC + (size_t)bh * 1024 * 128;
  const f16* Krb = KCr + (size_t)bh * 1024 * 128;
  const f16* Kib = KCi + (size_t)bh * 1024 * 128;
  const f16* Vb = VCT + (size_t)bh * 128 * 1024;

  f16x8 qf[8];
#pragma unroll
  for (int c = 0; c < 8; ++c)
    qf[c] = *(const f16x8*)&Qb[(size_t)(q0 + lq) * 128 + c * 16 + hi * 8];

  f32x16 accR[4] = {};
  f32x16 accI[4] = {};
  float m_r = -1e30f, l_r = 0.f, m_i = -1e30f, l_i = 0.f;

  const int sprow = tid >> 3;
  const int cK = (tid & 7) ^ ((tid >> 4) & 7);
  const f16* gKr = Krb + (size_t)(tid >> 4) * 128 + ((tid >> 3) & 1) * 64 + cK * 8;
  const f16* gKi = Kib + (size_t)(tid >> 4) * 128 + ((tid >> 3) & 1) * 64 + cK * 8;
  const int cV = (tid & 7) ^ (sprow & 7);
  const f16* gV = Vb + (size_t)(sprow * 2 + (cV >> 2)) * 1024 + (cV & 3) * 8;
  const int ldsW = w * 512;

#define STAGE(s, k0)                                                 \
  do {                                                               \
    load_lds16(gKr + (size_t)(k0) * 128, &sKr[s][ldsW]);             \
    load_lds16(gKi + (size_t)(k0) * 128, &sKi[s][ldsW]);             \
    load_lds16(gV + (k0), &sV[s][ldsW]);                             \
  } while (0)

  STAGE(0, 0);
  asm volatile("s_waitcnt vmcnt(0)" ::: "memory");
  __syncthreads();
  int cur = 0;

  for (int t = 0; t < 32; ++t) {
    if (t < 31) STAGE(cur ^ 1, (t + 1) * 32);

    f32x16 sr = {}, si = {};
    __builtin_amdgcn_s_setprio(1);
#pragma unroll
    for (int c = 0; c < 8; ++c) {
      int fc = c * 2 + hi;
      int prow = lq * 2 + (fc >> 3);
      int swzc = (fc & 7) ^ (lq & 7);
      f16x8 kr = *(const f16x8*)&sKr[cur][prow * 64 + swzc * 8];
      f16x8 ki = *(const f16x8*)&sKi[cur][prow * 64 + swzc * 8];
      sr = MFMA32(kr, qf[c], sr);
      si = MFMA32(ki, qf[c], si);
    }
    __builtin_amdgcn_s_setprio(0);

    f16x8 prf[2], pif[2];
#pragma unroll
    for (int part = 0; part < 2; ++part) {
      const f32x16& s = part ? si : sr;
      float& m = part ? m_i : m_r;
      float& lsum = part ? l_i : l_r;
      f32x16* acc = part ? accI : accR;
      float vm = s[0];
#pragma unroll
      for (int j = 1; j < 16; ++j) vm = fmaxf(vm, s[j]);
      vm = fmaxf(vm, __shfl_xor(vm, 32));
      if (__any(vm > m + 8.f)) {
        float mn = fmaxf(m, vm);
        float sc = __expf(m - mn);
        lsum *= sc;
#pragma unroll
        for (int a = 0; a < 4; ++a)
#pragma unroll
          for (int j = 0; j < 16; ++j) acc[a][j] *= sc;
        m = mn;
      }
      float p[16];
      float ls = 0.f;
#pragma unroll
      for (int j = 0; j < 16; ++j) { p[j] = __expf(s[j] - m); ls += p[j]; }
      lsum += ls;
      unsigned a0 = pkrtz(p[0], p[1]), b0 = pkrtz(p[4], p[5]);
      unsigned a1 = pkrtz(p[2], p[3]), b1 = pkrtz(p[6], p[7]);
      unsigned a2 = pkrtz(p[8], p[9]), b2 = pkrtz(p[12], p[13]);
      unsigned a3 = pkrtz(p[10], p[11]), b3 = pkrtz(p[14], p[15]);
      asm("v_permlane32_swap_b32 %0, %1" : "+v"(a0), "+v"(b0));
      asm("v_permlane32_swap_b32 %0, %1" : "+v"(a1), "+v"(b1));
      asm("v_permlane32_swap_b32 %0, %1" : "+v"(a2), "+v"(b2));
      asm("v_permlane32_swap_b32 %0, %1" : "+v"(a3), "+v"(b3));
      union { unsigned u[4]; f16x8 v; } f0, f1;
      f0.u[0] = a0; f0.u[1] = a1; f0.u[2] = b0; f0.u[3] = b1;
      f1.u[0] = a2; f1.u[1] = a3; f1.u[2] = b2; f1.u[3] = b3;
      if (part) { pif[0] = f0.v; pif[1] = f1.v; }
      else      { prf[0] = f0.v; prf[1] = f1.v; }
    }

    __builtin_amdgcn_s_setprio(1);
#pragma unroll
    for (int ft = 0; ft < 4; ++ft) {
#pragma unroll
      for (int ks = 0; ks < 2; ++ks) {
        int feat = ft * 32 + lq;
        int prow = feat >> 1;
        int swzc = (((feat & 1) * 4 + ks * 2 + hi) ^ (prow & 7));
        f16x8 vf = *(const f16x8*)&sV[cur][prow * 64 + swzc * 8];
        accR[ft] = MFMA32(vf, prf[ks], accR[ft]);
        accI[ft] = MFMA32(vf, pif[ks], accI[ft]);
      }
    }
    __builtin_amdgcn_s_setprio(0);

    asm volatile("s_waitcnt vmcnt(0)" ::: "memory");
    __syncthreads();
    cur ^= 1;
  }
#undef STAGE

  float lr = l_r + __shfl_xor(l_r, 32);
  float li = l_i + __shfl_xor(l_i, 32);
  float ilr = 1.f / lr, ili = 1.f / li;
  const int bb = bh >> 4, h = bh & 15;
  const int q = q0 + lq;
  f16* rowp = OC + ((size_t)bb * 1024 + q) * 2048 + h * 64;
#pragma unroll
  for (int tt = 0; tt < 2; ++tt) {
#pragma unroll
    for (int g = 0; g < 4; ++g) {
      int d0 = tt * 32 + g * 8 + hi * 4;
      f16x4 ov, oiv;
#pragma unroll
      for (int j = 0; j < 4; ++j) {
        int rg = g * 4 + j;
        float orv = accR[tt][rg] * ilr - accI[tt + 2][rg] * ili;
        float oivv = accR[tt + 2][rg] * ilr + accI[tt][rg] * ili;
        ov[j] = (f16)orv;
        oiv[j] = (f16)oivv;
      }
      *(f16x4*)(rowp + d0) = ov;
      *(f16x4*)(rowp + 1024 + d0) = oiv;
    }
  }
}

// ---------------- launcher ----------------------------------------------------

extern "C" void kernel_launch(void* const* d_in, const int* in_sizes, int n_in,
                              void* d_out, int out_size, void* d_ws, size_t ws_size,
                              hipStream_t stream) {
  const float* xr = (const float*)d_in[0];
  const float* xi = (const float*)d_in[1];
  const float* wpr = (const float*)d_in[2];
  const float* wpi = (const float*)d_in[3];
  const float* bpr = (const float*)d_in[4];
  const float* bpi = (const float*)d_in[5];
  const float* wor = (const float*)d_in[6];
  const float* woi = (const float*)d_in[7];
  const float* bor = (const float*)d_in[8];
  const float* boi = (const float*)d_in[9];

  f16* ws = (f16*)d_ws;
  f16* XC = ws;                       // 4096*2048
  f16* WQKV = XC + 8388608;           // 6144*2048
  f16* QC = WQKV + 12582912;          // 64*1024*128
  f16* KCr = QC + 8388608;
  f16* KCi = KCr + 8388608;
  f16* VCT = KCi + 8388608;           // 64*128*1024
  f16* OC = VCT + 8388608;            // 4096*2048
  f16* WOUT = OC + 8388608;           // 2048*2048

  pack_x_kernel<<<8192, 256, 0, stream>>>(xr, xi, XC);
  pack_wqkv_kernel<<<12288, 256, 0, stream>>>(wpr, wpi, WQKV);
  pack_wout_kernel<<<4096, 256, 0, stream>>>(wor, woi, WOUT);

  GemmParams p1 = {};
  p1.QC = QC; p1.KCr = KCr; p1.KCi = KCi; p1.VCT = VCT;
  p1.bpr = bpr; p1.bpi = bpi;
  // 16 m-tiles x 24 n-tiles (8 XCD x 3)
  gemm1_kernel<<<384, 512, 0, stream>>>(XC, WQKV, p1);

  attn_kernel<<<256, 512, 0, stream>>>(QC, KCr, KCi, VCT, OC);

  GemmParams p2 = {};
  p2.out = (float*)d_out; p2.bor = bor; p2.boi = boi;
  p2.out_complex = (out_size == 8388608) ? 1 : 0;
  int ntilesN = p2.out_complex ? 16 : 8;
  gemm_out_kernel<<<dim3(ntilesN, 32), 256, 0, stream>>>(OC, WOUT, p2);
}

// Round 9
// 296.596 us; speedup vs baseline: 1.0879x; 1.0060x over previous
//
#include <hip/hip_runtime.h>

// Complex MHA, B=4 S=1024 E=1024 H=16 DH=64.
// pack(fp32->fp16, K-concat complex trick) -> GEMM1 (128^2 BK=32 dbuf, 4 blocks/CU,
// prefetch-issue-first, XCD-chunked, scatter epilogue) -> flash complex attention
// (swapped-operand 32x32) -> GEMM2 (m97 128^2).

typedef _Float16 f16;
typedef _Float16 f16x8 __attribute__((ext_vector_type(8)));
typedef _Float16 f16x4 __attribute__((ext_vector_type(4)));
typedef float f32x4 __attribute__((ext_vector_type(4)));
typedef float f32x16 __attribute__((ext_vector_type(16)));

#define MFMA16(a, b, c) __builtin_amdgcn_mfma_f32_16x16x32_f16(a, b, c, 0, 0, 0)
#define MFMA32(a, b, c) __builtin_amdgcn_mfma_f32_32x32x16_f16(a, b, c, 0, 0, 0)

__device__ inline void load_lds16(const void* g, void* l) {
  __builtin_amdgcn_global_load_lds(
      (const __attribute__((address_space(1))) unsigned int*)g,
      (__attribute__((address_space(3))) unsigned int*)l, 16, 0, 0);
}

__device__ inline unsigned pkrtz(float a, float b) {
  auto t = __builtin_amdgcn_cvt_pkrtz(a, b);
  return __builtin_bit_cast(unsigned, t);
}

// ---------------- pack kernels (fp32 -> fp16, concat layouts) ----------------

__global__ void pack_x_kernel(const float* __restrict__ xr, const float* __restrict__ xi,
                              f16* __restrict__ XC) {
  int i = blockIdx.x * 256 + threadIdx.x;
  if (i >= (4096 * 2048 / 4)) return;
  int idx = i * 4;
  int m = idx >> 11, k = idx & 2047;
  const float* src = (k < 1024) ? (xr + (size_t)m * 1024 + k) : (xi + (size_t)m * 1024 + k - 1024);
  float4 v = *(const float4*)src;
  f16x4 o = {(f16)v.x, (f16)v.y, (f16)v.z, (f16)v.w};
  *(f16x4*)(XC + idx) = o;
}

__global__ void pack_wqkv_kernel(const float* __restrict__ wr, const float* __restrict__ wi,
                                 f16* __restrict__ W) {
  int i = blockIdx.x * 256 + threadIdx.x;
  if (i >= (6144 * 2048 / 4)) return;
  int idx = i * 4;
  int n = idx >> 11, k = idx & 2047;
  const float* base;
  float sgn = 1.f;
  if (n < 3072) {
    if (k < 1024) base = wr + (size_t)n * 1024 + k;
    else { base = wi + (size_t)n * 1024 + k - 1024; sgn = -1.f; }
  } else {
    int n2 = n - 3072;
    if (k < 1024) base = wi + (size_t)n2 * 1024 + k;
    else base = wr + (size_t)n2 * 1024 + k - 1024;
  }
  float4 v = *(const float4*)base;
  f16x4 o = {(f16)(sgn * v.x), (f16)(sgn * v.y), (f16)(sgn * v.z), (f16)(sgn * v.w)};
  *(f16x4*)(W + idx) = o;
}

__global__ void pack_wout_kernel(const float* __restrict__ wor, const float* __restrict__ woi,
                                 f16* __restrict__ W) {
  int i = blockIdx.x * 256 + threadIdx.x;
  if (i >= (2048 * 2048 / 4)) return;
  int idx = i * 4;
  int n = idx >> 11, k = idx & 2047;
  const float* base;
  float sgn = 1.f;
  if (n < 1024) {
    if (k < 1024) base = wor + (size_t)n * 1024 + k;
    else { base = woi + (size_t)n * 1024 + k - 1024; sgn = -1.f; }
  } else {
    int n2 = n - 1024;
    if (k < 1024) base = woi + (size_t)n2 * 1024 + k;
    else base = wor + (size_t)n2 * 1024 + k - 1024;
  }
  float4 v = *(const float4*)base;
  f16x4 o = {(f16)(sgn * v.x), (f16)(sgn * v.y), (f16)(sgn * v.z), (f16)(sgn * v.w)};
  *(f16x4*)(W + idx) = o;
}

struct GemmParams {
  f16 *QC, *KCr, *KCi, *VCT;
  const float *bpr, *bpi;
  float* out;
  const float *bor, *boi;
  int out_complex;
};

// ---------------- GEMM1: 128^2 BK=32 dbuf, 4 waves, 4 blocks/CU ---------------
// C[4096, 6144] = A[4096,2048] * B[6144,2048]^T, scatter epilogue.
// LDS rows are 64B (32 f16); chunk position = lk ^ ((row>>1)&3) -> 2-way/bank.

__global__ __launch_bounds__(256, 4) void gemm1_kernel(const f16* __restrict__ A,
                                                       const f16* __restrict__ B,
                                                       GemmParams p) {
  const int K = 2048;
  __shared__ alignas(16) f16 sA[2][128 * 32];
  __shared__ alignas(16) f16 sB[2][128 * 32];
  const int tid = threadIdx.x;
  const int w = tid >> 6, l = tid & 63;
  const int lr = l & 15, lk = l >> 4;
  // XCD-chunked: xcd = lin&7 owns 6 n-tiles x 32 m-tiles, n-fastest (A reuse)
  const int lin = blockIdx.x;
  const int xcd = lin & 7, idx = lin >> 3;
  const int mt = idx / 6, ntl = idx % 6;
  const int tm0 = mt * 128;
  const int tn0 = (xcd * 6 + ntl) * 128;
  const int wm = (w >> 1) * 64, wn = (w & 1) * 64;

  // staging: linear LDS dest; source chunk pre-applies inverse swizzle.
  // thread covers logical row tid>>2, position tid&3; source chunk = pos^((row>>1)&3)
  const int srcC = ((tid & 3) ^ ((tid >> 3) & 3)) * 8;
  const f16* gA = A + (size_t)(tm0 + (tid >> 2)) * K + srcC;
  const f16* gB = B + (size_t)(tn0 + (tid >> 2)) * K + srcC;
  const int dst = w * 512;  // f16, wave-uniform piece of each 2048-f16 call region

#define STG(buf, k0) do {                                        \
    load_lds16(gA + (k0), &sA[buf][dst]);                        \
    load_lds16(gA + (size_t)64 * K + (k0), &sA[buf][2048 + dst]);\
    load_lds16(gB + (k0), &sB[buf][dst]);                        \
    load_lds16(gB + (size_t)64 * K + (k0), &sB[buf][2048 + dst]);\
  } while (0)

  f32x4 acc[4][4] = {};

  STG(0, 0);
  asm volatile("s_waitcnt vmcnt(0)" ::: "memory");
  __syncthreads();
  int cur = 0;

  for (int t = 0; t < 64; ++t) {
    if (t < 63) STG(cur ^ 1, (t + 1) * 32);
    f16x8 af[4], bf[4];
#pragma unroll
    for (int i = 0; i < 4; ++i) {
      int rowA = wm + i * 16 + lr;
      af[i] = *(const f16x8*)&sA[cur][rowA * 32 + (lk ^ ((rowA >> 1) & 3)) * 8];
      int rowB = wn + i * 16 + lr;
      bf[i] = *(const f16x8*)&sB[cur][rowB * 32 + (lk ^ ((rowB >> 1) & 3)) * 8];
    }
#pragma unroll
    for (int mi = 0; mi < 4; ++mi)
#pragma unroll
      for (int nj = 0; nj < 4; ++nj)
        acc[mi][nj] = MFMA16(af[mi], bf[nj], acc[mi][nj]);
    asm volatile("s_waitcnt vmcnt(0)" ::: "memory");
    __syncthreads();
    cur ^= 1;
  }
#undef STG

  // ---- scatter epilogue (16x16 C/D: col=lane&15, row=lk*4+r) ----
#pragma unroll
  for (int mi = 0; mi < 4; ++mi)
#pragma unroll
    for (int nj = 0; nj < 4; ++nj) {
      int n = tn0 + wn + nj * 16 + lr;
      bool im = n >= 3072;
      int nn = im ? n - 3072 : n;
      float bias = im ? p.bpi[nn] : p.bpr[nn];
      int part = nn >> 10;
      int e = nn & 1023, h = e >> 6, dd = e & 63;
      int m0 = tm0 + wm + mi * 16 + lk * 4;
      int bb = m0 >> 10, s0 = m0 & 1023;
      size_t bh = (size_t)bb * 16 + h;
      if (part == 0) {
#pragma unroll
        for (int r = 0; r < 4; ++r)
          p.QC[(bh * 1024 + s0 + r) * 128 + (im ? 64 : 0) + dd] =
              (f16)((acc[mi][nj][r] + bias) * 0.125f);
      } else if (part == 1) {
#pragma unroll
        for (int r = 0; r < 4; ++r) {
          float v2 = acc[mi][nj][r] + bias;
          size_t o = (bh * 1024 + s0 + r) * 128;
          if (!im) { p.KCr[o + dd] = (f16)v2; p.KCi[o + 64 + dd] = (f16)v2; }
          else     { p.KCr[o + 64 + dd] = (f16)(-v2); p.KCi[o + dd] = (f16)v2; }
        }
      } else {
        f16x4 vv;
#pragma unroll
        for (int r = 0; r < 4; ++r) vv[r] = (f16)(acc[mi][nj][r] + bias);
        *(f16x4*)&p.VCT[((bh * 128 + (im ? 64 : 0) + dd)) * 1024 + s0] = vv;
      }
    }
}

// ---------------- GEMM2 (out proj): m97 128^2, proven 0-conflict --------------

__global__ __launch_bounds__(256) void gemm_out_kernel(const f16* __restrict__ A,
                                                       const f16* __restrict__ B,
                                                       GemmParams p) {
  const int K = 2048;
  __shared__ alignas(16) f16 sA[128 * 64];
  __shared__ alignas(16) f16 sB[128 * 64];
  const int tid = threadIdx.x;
  const int w = tid >> 6, l = tid & 63;
  const int lr = l & 15, lk = l >> 4;
  const int nwg = gridDim.x * gridDim.y;
  const int lin = blockIdx.y * gridDim.x + blockIdx.x;
  const int qq = nwg >> 3, rr = nwg & 7;
  const int xcd = lin & 7, off = lin >> 3;
  const int swz = (xcd < rr ? xcd * (qq + 1) : rr * (qq + 1) + (xcd - rr) * qq) + off;
  const int tm0 = (swz / gridDim.x) * 128;
  const int tn0 = (swz % gridDim.x) * 128;
  const int wm = (w >> 1) * 64, wn = (w & 1) * 64;

  f32x4 acc[4][4] = {};

  for (int k0 = 0; k0 < K; k0 += 64) {
#pragma unroll
    for (int i = 0; i < 4; ++i) {
      int slot = i * 256 + tid;
      int row = slot >> 3;
      int cg = (slot & 7) ^ (row & 7);
      load_lds16(A + (size_t)(tm0 + row) * K + k0 + cg * 8, &sA[(size_t)(i * 256 + (w << 6)) * 8]);
      load_lds16(B + (size_t)(tn0 + row) * K + k0 + cg * 8, &sB[(size_t)(i * 256 + (w << 6)) * 8]);
    }
    __syncthreads();
#pragma unroll
    for (int kk = 0; kk < 2; ++kk) {
      f16x8 af[4], bf[4];
#pragma unroll
      for (int t = 0; t < 4; ++t) {
        int rowA = wm + t * 16 + lr;
        af[t] = *(const f16x8*)&sA[rowA * 64 + ((kk * 4 + lk) ^ (rowA & 7)) * 8];
        int rowB = wn + t * 16 + lr;
        bf[t] = *(const f16x8*)&sB[rowB * 64 + ((kk * 4 + lk) ^ (rowB & 7)) * 8];
      }
#pragma unroll
      for (int mt = 0; mt < 4; ++mt)
#pragma unroll
        for (int nt = 0; nt < 4; ++nt) acc[mt][nt] = MFMA16(af[mt], bf[nt], acc[mt][nt]);
    }
    __syncthreads();
  }

#pragma unroll
  for (int mt = 0; mt < 4; ++mt)
#pragma unroll
    for (int nt = 0; nt < 4; ++nt)
#pragma unroll
      for (int r = 0; r < 4; ++r) {
        int m = tm0 + wm + mt * 16 + lk * 4 + r;
        int n = tn0 + wn + nt * 16 + lr;
        float val = acc[mt][nt][r];
        if (n < 1024) {
          float v2 = val + p.bor[n];
          if (p.out_complex) p.out[((size_t)m * 1024 + n) * 2] = v2;
          else p.out[(size_t)m * 1024 + n] = v2;
        } else {
          if (p.out_complex) p.out[((size_t)m * 1024 + n - 1024) * 2 + 1] = val + p.boi[n - 1024];
        }
      }
}

// ---------------- flash complex attention (swapped-operand 32x32) -------------

__global__ __launch_bounds__(512, 2) void attn_kernel(const f16* __restrict__ QC,
                                                      const f16* __restrict__ KCr,
                                                      const f16* __restrict__ KCi,
                                                      const f16* __restrict__ VCT,
                                                      f16* __restrict__ OC) {
  __shared__ alignas(16) f16 sKr[2][32 * 128];
  __shared__ alignas(16) f16 sKi[2][32 * 128];
  __shared__ alignas(16) f16 sV[2][128 * 32];
  const int tid = threadIdx.x;
  const int w = tid >> 6, l = tid & 63;
  const int lq = l & 31, hi = l >> 5;
  const int bid = blockIdx.x;
  const int xx = bid & 7, yy = bid >> 3;
  const int bh = xx + ((yy >> 2) << 3);
  const int qt = yy & 3;
  const int q0 = qt * 256 + w * 32;
  const f16* Qb = QC + (size_t)bh * 1024 * 128;
  const f16* Krb = KCr + (size_t)bh * 1024 * 128;
  const f16* Kib = KCi + (size_t)bh * 1024 * 128;
  const f16* Vb = VCT + (size_t)bh * 128 * 1024;

  f16x8 qf[8];
#pragma unroll
  for (int c = 0; c < 8; ++c)
    qf[c] = *(const f16x8*)&Qb[(size_t)(q0 + lq) * 128 + c * 16 + hi * 8];

  f32x16 accR[4] = {};
  f32x16 accI[4] = {};
  float m_r = -1e30f, l_r = 0.f, m_i = -1e30f, l_i = 0.f;

  const int sprow = tid >> 3;
  const int cK = (tid & 7) ^ ((tid >> 4) & 7);
  const f16* gKr = Krb + (size_t)(tid >> 4) * 128 + ((tid >> 3) & 1) * 64 + cK * 8;
  const f16* gKi = Kib + (size_t)(tid >> 4) * 128 + ((tid >> 3) & 1) * 64 + cK * 8;
  const int cV = (tid & 7) ^ (sprow & 7);
  const f16* gV = Vb + (size_t)(sprow * 2 + (cV >> 2)) * 1024 + (cV & 3) * 8;
  const int ldsW = w * 512;

#define STAGE(s, k0)                                                 \
  do {                                                               \
    load_lds16(gKr + (size_t)(k0) * 128, &sKr[s][ldsW]);             \
    load_lds16(gKi + (size_t)(k0) * 128, &sKi[s][ldsW]);             \
    load_lds16(gV + (k0), &sV[s][ldsW]);                             \
  } while (0)

  STAGE(0, 0);
  asm volatile("s_waitcnt vmcnt(0)" ::: "memory");
  __syncthreads();
  int cur = 0;

  for (int t = 0; t < 32; ++t) {
    if (t < 31) STAGE(cur ^ 1, (t + 1) * 32);

    f32x16 sr = {}, si = {};
    __builtin_amdgcn_s_setprio(1);
#pragma unroll
    for (int c = 0; c < 8; ++c) {
      int fc = c * 2 + hi;
      int prow = lq * 2 + (fc >> 3);
      int swzc = (fc & 7) ^ (lq & 7);
      f16x8 kr = *(const f16x8*)&sKr[cur][prow * 64 + swzc * 8];
      f16x8 ki = *(const f16x8*)&sKi[cur][prow * 64 + swzc * 8];
      sr = MFMA32(kr, qf[c], sr);
      si = MFMA32(ki, qf[c], si);
    }
    __builtin_amdgcn_s_setprio(0);

    f16x8 prf[2], pif[2];
#pragma unroll
    for (int part = 0; part < 2; ++part) {
      const f32x16& s = part ? si : sr;
      float& m = part ? m_i : m_r;
      float& lsum = part ? l_i : l_r;
      f32x16* acc = part ? accI : accR;
      float vm = s[0];
#pragma unroll
      for (int j = 1; j < 16; ++j) vm = fmaxf(vm, s[j]);
      vm = fmaxf(vm, __shfl_xor(vm, 32));
      if (__any(vm > m + 8.f)) {
        float mn = fmaxf(m, vm);
        float sc = __expf(m - mn);
        lsum *= sc;
#pragma unroll
        for (int a = 0; a < 4; ++a)
#pragma unroll
          for (int j = 0; j < 16; ++j) acc[a][j] *= sc;
        m = mn;
      }
      float p[16];
      float ls = 0.f;
#pragma unroll
      for (int j = 0; j < 16; ++j) { p[j] = __expf(s[j] - m); ls += p[j]; }
      lsum += ls;
      unsigned a0 = pkrtz(p[0], p[1]), b0 = pkrtz(p[4], p[5]);
      unsigned a1 = pkrtz(p[2], p[3]), b1 = pkrtz(p[6], p[7]);
      unsigned a2 = pkrtz(p[8], p[9]), b2 = pkrtz(p[12], p[13]);
      unsigned a3 = pkrtz(p[10], p[11]), b3 = pkrtz(p[14], p[15]);
      asm("v_permlane32_swap_b32 %0, %1" : "+v"(a0), "+v"(b0));
      asm("v_permlane32_swap_b32 %0, %1" : "+v"(a1), "+v"(b1));
      asm("v_permlane32_swap_b32 %0, %1" : "+v"(a2), "+v"(b2));
      asm("v_permlane32_swap_b32 %0, %1" : "+v"(a3), "+v"(b3));
      union { unsigned u[4]; f16x8 v; } f0, f1;
      f0.u[0] = a0; f0.u[1] = a1; f0.u[2] = b0; f0.u[3] = b1;
      f1.u[0] = a2; f1.u[1] = a3; f1.u[2] = b2; f1.u[3] = b3;
      if (part) { pif[0] = f0.v; pif[1] = f1.v; }
      else      { prf[0] = f0.v; prf[1] = f1.v; }
    }

    __builtin_amdgcn_s_setprio(1);
#pragma unroll
    for (int ft = 0; ft < 4; ++ft) {
#pragma unroll
      for (int ks = 0; ks < 2; ++ks) {
        int feat = ft * 32 + lq;
        int prow = feat >> 1;
        int swzc = (((feat & 1) * 4 + ks * 2 + hi) ^ (prow & 7));
        f16x8 vf = *(const f16x8*)&sV[cur][prow * 64 + swzc * 8];
        accR[ft] = MFMA32(vf, prf[ks], accR[ft]);
        accI[ft] = MFMA32(vf, pif[ks], accI[ft]);
      }
    }
    __builtin_amdgcn_s_setprio(0);

    asm volatile("s_waitcnt vmcnt(0)" ::: "memory");
    __syncthreads();
    cur ^= 1;
  }
#undef STAGE

  float lr = l_r + __shfl_xor(l_r, 32);
  float li = l_i + __shfl_xor(l_i, 32);
  float ilr = 1.f / lr, ili = 1.f / li;
  const int bb = bh >> 4, h = bh & 15;
  const int q = q0 + lq;
  f16* rowp = OC + ((size_t)bb * 1024 + q) * 2048 + h * 64;
#pragma unroll
  for (int tt = 0; tt < 2; ++tt) {
#pragma unroll
    for (int g = 0; g < 4; ++g) {
      int d0 = tt * 32 + g * 8 + hi * 4;
      f16x4 ov, oiv;
#pragma unroll
      for (int j = 0; j < 4; ++j) {
        int rg = g * 4 + j;
        float orv = accR[tt][rg] * ilr - accI[tt + 2][rg] * ili;
        float oivv = accR[tt + 2][rg] * ilr + accI[tt][rg] * ili;
        ov[j] = (f16)orv;
        oiv[j] = (f16)oivv;
      }
      *(f16x4*)(rowp + d0) = ov;
      *(f16x4*)(rowp + 1024 + d0) = oiv;
    }
  }
}

// ---------------- launcher ----------------------------------------------------

extern "C" void kernel_launch(void* const* d_in, const int* in_sizes, int n_in,
                              void* d_out, int out_size, void* d_ws, size_t ws_size,
                              hipStream_t stream) {
  const float* xr = (const float*)d_in[0];
  const float* xi = (const float*)d_in[1];
  const float* wpr = (const float*)d_in[2];
  const float* wpi = (const float*)d_in[3];
  const float* bpr = (const float*)d_in[4];
  const float* bpi = (const float*)d_in[5];
  const float* wor = (const float*)d_in[6];
  const float* woi = (const float*)d_in[7];
  const float* bor = (const float*)d_in[8];
  const float* boi = (const float*)d_in[9];

  f16* ws = (f16*)d_ws;
  f16* XC = ws;                       // 4096*2048
  f16* WQKV = XC + 8388608;           // 6144*2048
  f16* QC = WQKV + 12582912;          // 64*1024*128
  f16* KCr = QC + 8388608;
  f16* KCi = KCr + 8388608;
  f16* VCT = KCi + 8388608;           // 64*128*1024
  f16* OC = VCT + 8388608;            // 4096*2048
  f16* WOUT = OC + 8388608;           // 2048*2048

  pack_x_kernel<<<8192, 256, 0, stream>>>(xr, xi, XC);
  pack_wqkv_kernel<<<12288, 256, 0, stream>>>(wpr, wpi, WQKV);
  pack_wout_kernel<<<4096, 256, 0, stream>>>(wor, woi, WOUT);

  GemmParams p1 = {};
  p1.QC = QC; p1.KCr = KCr; p1.KCi = KCi; p1.VCT = VCT;
  p1.bpr = bpr; p1.bpi = bpi;
  // 8 XCD x (32 m-tiles x 6 n-tiles) = 1536 blocks
  gemm1_kernel<<<1536, 256, 0, stream>>>(XC, WQKV, p1);

  attn_kernel<<<256, 512, 0, stream>>>(QC, KCr, KCi, VCT, OC);

  GemmParams p2 = {};
  p2.out = (float*)d_out; p2.bor = bor; p2.boi = boi;
  p2.out_complex = (out_size == 8388608) ? 1 : 0;
  int ntilesN = p2.out_complex ? 16 : 8;
  gemm_out_kernel<<<dim3(ntilesN, 32), 256, 0, stream>>>(OC, WOUT, p2);
}

// Round 10
// 284.139 us; speedup vs baseline: 1.1356x; 1.0438x over previous
//
#include <hip/hip_runtime.h>

// Complex MHA, B=4 S=1024 E=1024 H=16 DH=64.
// pack(fp32->fp16, K-concat complex trick) -> GEMM1 (128^2 BK=64 single-buf,
// 32x32x16 MFMA, dual-B-style fragments, 4 blocks/CU, scatter epilogue) ->
// flash complex attention (swapped-operand 32x32) -> GEMM2 (same template).

typedef _Float16 f16;
typedef _Float16 f16x8 __attribute__((ext_vector_type(8)));
typedef _Float16 f16x4 __attribute__((ext_vector_type(4)));
typedef float f32x4 __attribute__((ext_vector_type(4)));
typedef float f32x16 __attribute__((ext_vector_type(16)));

#define MFMA16(a, b, c) __builtin_amdgcn_mfma_f32_16x16x32_f16(a, b, c, 0, 0, 0)
#define MFMA32(a, b, c) __builtin_amdgcn_mfma_f32_32x32x16_f16(a, b, c, 0, 0, 0)

__device__ inline void load_lds16(const void* g, void* l) {
  __builtin_amdgcn_global_load_lds(
      (const __attribute__((address_space(1))) unsigned int*)g,
      (__attribute__((address_space(3))) unsigned int*)l, 16, 0, 0);
}

__device__ inline unsigned pkrtz(float a, float b) {
  auto t = __builtin_amdgcn_cvt_pkrtz(a, b);
  return __builtin_bit_cast(unsigned, t);
}

// ---------------- pack kernels (fp32 -> fp16, concat layouts) ----------------

__global__ void pack_x_kernel(const float* __restrict__ xr, const float* __restrict__ xi,
                              f16* __restrict__ XC) {
  int i = blockIdx.x * 256 + threadIdx.x;
  if (i >= (4096 * 2048 / 4)) return;
  int idx = i * 4;
  int m = idx >> 11, k = idx & 2047;
  const float* src = (k < 1024) ? (xr + (size_t)m * 1024 + k) : (xi + (size_t)m * 1024 + k - 1024);
  float4 v = *(const float4*)src;
  f16x4 o = {(f16)v.x, (f16)v.y, (f16)v.z, (f16)v.w};
  *(f16x4*)(XC + idx) = o;
}

__global__ void pack_wqkv_kernel(const float* __restrict__ wr, const float* __restrict__ wi,
                                 f16* __restrict__ W) {
  int i = blockIdx.x * 256 + threadIdx.x;
  if (i >= (6144 * 2048 / 4)) return;
  int idx = i * 4;
  int n = idx >> 11, k = idx & 2047;
  const float* base;
  float sgn = 1.f;
  if (n < 3072) {
    if (k < 1024) base = wr + (size_t)n * 1024 + k;
    else { base = wi + (size_t)n * 1024 + k - 1024; sgn = -1.f; }
  } else {
    int n2 = n - 3072;
    if (k < 1024) base = wi + (size_t)n2 * 1024 + k;
    else base = wr + (size_t)n2 * 1024 + k - 1024;
  }
  float4 v = *(const float4*)base;
  f16x4 o = {(f16)(sgn * v.x), (f16)(sgn * v.y), (f16)(sgn * v.z), (f16)(sgn * v.w)};
  *(f16x4*)(W + idx) = o;
}

__global__ void pack_wout_kernel(const float* __restrict__ wor, const float* __restrict__ woi,
                                 f16* __restrict__ W) {
  int i = blockIdx.x * 256 + threadIdx.x;
  if (i >= (2048 * 2048 / 4)) return;
  int idx = i * 4;
  int n = idx >> 11, k = idx & 2047;
  const float* base;
  float sgn = 1.f;
  if (n < 1024) {
    if (k < 1024) base = wor + (size_t)n * 1024 + k;
    else { base = woi + (size_t)n * 1024 + k - 1024; sgn = -1.f; }
  } else {
    int n2 = n - 1024;
    if (k < 1024) base = woi + (size_t)n2 * 1024 + k;
    else base = wor + (size_t)n2 * 1024 + k - 1024;
  }
  float4 v = *(const float4*)base;
  f16x4 o = {(f16)(sgn * v.x), (f16)(sgn * v.y), (f16)(sgn * v.z), (f16)(sgn * v.w)};
  *(f16x4*)(W + idx) = o;
}

struct GemmParams {
  f16 *QC, *KCr, *KCi, *VCT;
  const float *bpr, *bpi;
  float* out;
  const float *bor, *boi;
  int out_complex;
};

// ---------------- GEMM: 128^2 BK=64, 32x32x16 MFMA, single-buf, 4 blk/CU ------
// C[M,N] = A[M,2048] * B[N,2048]^T. Wave tile 64x64 (2x2 MFMA32 tiles).
// Both operand tiles stored [row][64 f16] 128B rows, chunk ^= (row&7) (R5-proven).

template <int MODE>
__global__ __launch_bounds__(256, 4) void gemm_kernel(const f16* __restrict__ A,
                                                      const f16* __restrict__ B,
                                                      GemmParams p, int ntPerXcd) {
  const int K = 2048;
  __shared__ alignas(16) f16 sA[128 * 64];
  __shared__ alignas(16) f16 sB[128 * 64];
  const int tid = threadIdx.x;
  const int w = tid >> 6, l = tid & 63;
  const int lq = l & 31, hi = l >> 5;
  // XCD-chunked mapping: xcd = lin&7 owns ntPerXcd n-tiles x all m-tiles
  const int lin = blockIdx.x;
  const int xcd = lin & 7, idx = lin >> 3;
  const int mt = idx / ntPerXcd, ntl = idx % ntPerXcd;
  const int tm0 = mt * 128;
  const int tn0 = (xcd * ntPerXcd + ntl) * 128;
  const int wm = (w >> 1) * 64, wn = (w & 1) * 64;

  // staging (R5-proven): thread covers row srow+i*32, chunk scg (row&7 == srow&7)
  const int srow = tid >> 3;
  const int scg = (tid & 7) ^ (srow & 7);
  const f16* gA0 = A + (size_t)(tm0 + srow) * K + scg * 8;
  const ptrdiff_t dB = (B - A) + (ptrdiff_t)(tn0 - tm0) * K;
  const int dst0 = w * 512;  // f16 units, wave-uniform

  f32x16 acc[2][2] = {};

  for (int k0 = 0; k0 < K; k0 += 64) {
#pragma unroll
    for (int i = 0; i < 4; ++i) {
      load_lds16(gA0 + (size_t)i * 32 * K + k0, &sA[i * 2048 + dst0]);
      load_lds16(gA0 + dB + (size_t)i * 32 * K + k0, &sB[i * 2048 + dst0]);
    }
    __syncthreads();
#pragma unroll
    for (int ks = 0; ks < 4; ++ks) {
      f16x8 af[2], bf[2];
#pragma unroll
      for (int mi = 0; mi < 2; ++mi) {
        int row = wm + mi * 32 + lq;
        af[mi] = *(const f16x8*)&sA[row * 64 + (((ks * 2 + hi) ^ (row & 7)) * 8)];
      }
#pragma unroll
      for (int nj = 0; nj < 2; ++nj) {
        int row = wn + nj * 32 + lq;
        bf[nj] = *(const f16x8*)&sB[row * 64 + (((ks * 2 + hi) ^ (row & 7)) * 8)];
      }
#pragma unroll
      for (int mi = 0; mi < 2; ++mi)
#pragma unroll
        for (int nj = 0; nj < 2; ++nj)
          acc[mi][nj] = MFMA32(af[mi], bf[nj], acc[mi][nj]);
    }
    __syncthreads();
  }

  // ---- epilogue: MFMA32 C/D layout col=lane&31, row=(r&3)+8*(r>>2)+4*hi ----
#pragma unroll
  for (int mi = 0; mi < 2; ++mi)
#pragma unroll
    for (int nj = 0; nj < 2; ++nj) {
      int n = tn0 + wn + nj * 32 + lq;
      if constexpr (MODE == 0) {
        bool im = n >= 3072;
        int nn = im ? n - 3072 : n;
        float bias = im ? p.bpi[nn] : p.bpr[nn];
        int part = nn >> 10;
        int e = nn & 1023, h = e >> 6, dd = e & 63;
        size_t bhh = 0;
#pragma unroll
        for (int rg = 0; rg < 4; ++rg) {
          int m0 = tm0 + wm + mi * 32 + rg * 8 + hi * 4;
          int bb = m0 >> 10, s0 = m0 & 1023;
          size_t bh = (size_t)bb * 16 + h;
          (void)bhh;
          if (part == 0) {
#pragma unroll
            for (int j = 0; j < 4; ++j)
              p.QC[(bh * 1024 + s0 + j) * 128 + (im ? 64 : 0) + dd] =
                  (f16)((acc[mi][nj][rg * 4 + j] + bias) * 0.125f);
          } else if (part == 1) {
#pragma unroll
            for (int j = 0; j < 4; ++j) {
              float v2 = acc[mi][nj][rg * 4 + j] + bias;
              size_t o = (bh * 1024 + s0 + j) * 128;
              if (!im) { p.KCr[o + dd] = (f16)v2; p.KCi[o + 64 + dd] = (f16)v2; }
              else     { p.KCr[o + 64 + dd] = (f16)(-v2); p.KCi[o + dd] = (f16)v2; }
            }
          } else {
            f16x4 vv;
#pragma unroll
            for (int j = 0; j < 4; ++j) vv[j] = (f16)(acc[mi][nj][rg * 4 + j] + bias);
            *(f16x4*)&p.VCT[((bh * 128 + (im ? 64 : 0) + dd)) * 1024 + s0] = vv;
          }
        }
      } else {
        float bias = (n < 1024) ? p.bor[n] : p.boi[n - 1024];
#pragma unroll
        for (int rg = 0; rg < 4; ++rg) {
          int m0 = tm0 + wm + mi * 32 + rg * 8 + hi * 4;
#pragma unroll
          for (int j = 0; j < 4; ++j) {
            float v2 = acc[mi][nj][rg * 4 + j] + bias;
            size_t m = (size_t)(m0 + j);
            if (n < 1024) {
              if (p.out_complex) p.out[(m * 1024 + n) * 2] = v2;
              else p.out[m * 1024 + n] = v2;
            } else {
              if (p.out_complex) p.out[(m * 1024 + n - 1024) * 2 + 1] = v2;
            }
          }
        }
      }
    }
}

// ---------------- flash complex attention (swapped-operand 32x32) -------------

__global__ __launch_bounds__(512, 2) void attn_kernel(const f16* __restrict__ QC,
                                                      const f16* __restrict__ KCr,
                                                      const f16* __restrict__ KCi,
                                                      const f16* __restrict__ VCT,
                                                      f16* __restrict__ OC) {
  __shared__ alignas(16) f16 sKr[2][32 * 128];
  __shared__ alignas(16) f16 sKi[2][32 * 128];
  __shared__ alignas(16) f16 sV[2][128 * 32];
  const int tid = threadIdx.x;
  const int w = tid >> 6, l = tid & 63;
  const int lq = l & 31, hi = l >> 5;
  const int bid = blockIdx.x;
  const int xx = bid & 7, yy = bid >> 3;
  const int bh = xx + ((yy >> 2) << 3);
  const int qt = yy & 3;
  const int q0 = qt * 256 + w * 32;
  const f16* Qb = QC + (size_t)bh * 1024 * 128;
  const f16* Krb = KCr + (size_t)bh * 1024 * 128;
  const f16* Kib = KCi + (size_t)bh * 1024 * 128;
  const f16* Vb = VCT + (size_t)bh * 128 * 1024;

  f16x8 qf[8];
#pragma unroll
  for (int c = 0; c < 8; ++c)
    qf[c] = *(const f16x8*)&Qb[(size_t)(q0 + lq) * 128 + c * 16 + hi * 8];

  f32x16 accR[4] = {};
  f32x16 accI[4] = {};
  float m_r = -1e30f, l_r = 0.f, m_i = -1e30f, l_i = 0.f;

  const int sprow = tid >> 3;
  const int cK = (tid & 7) ^ ((tid >> 4) & 7);
  const f16* gKr = Krb + (size_t)(tid >> 4) * 128 + ((tid >> 3) & 1) * 64 + cK * 8;
  const f16* gKi = Kib + (size_t)(tid >> 4) * 128 + ((tid >> 3) & 1) * 64 + cK * 8;
  const int cV = (tid & 7) ^ (sprow & 7);
  const f16* gV = Vb + (size_t)(sprow * 2 + (cV >> 2)) * 1024 + (cV & 3) * 8;
  const int ldsW = w * 512;

#define STAGE(s, k0)                                                 \
  do {                                                               \
    load_lds16(gKr + (size_t)(k0) * 128, &sKr[s][ldsW]);             \
    load_lds16(gKi + (size_t)(k0) * 128, &sKi[s][ldsW]);             \
    load_lds16(gV + (k0), &sV[s][ldsW]);                             \
  } while (0)

  STAGE(0, 0);
  asm volatile("s_waitcnt vmcnt(0)" ::: "memory");
  __syncthreads();
  int cur = 0;

  for (int t = 0; t < 32; ++t) {
    if (t < 31) STAGE(cur ^ 1, (t + 1) * 32);

    f32x16 sr = {}, si = {};
    __builtin_amdgcn_s_setprio(1);
#pragma unroll
    for (int c = 0; c < 8; ++c) {
      int fc = c * 2 + hi;
      int prow = lq * 2 + (fc >> 3);
      int swzc = (fc & 7) ^ (lq & 7);
      f16x8 kr = *(const f16x8*)&sKr[cur][prow * 64 + swzc * 8];
      f16x8 ki = *(const f16x8*)&sKi[cur][prow * 64 + swzc * 8];
      sr = MFMA32(kr, qf[c], sr);
      si = MFMA32(ki, qf[c], si);
    }
    __builtin_amdgcn_s_setprio(0);

    f16x8 prf[2], pif[2];
#pragma unroll
    for (int part = 0; part < 2; ++part) {
      const f32x16& s = part ? si : sr;
      float& m = part ? m_i : m_r;
      float& lsum = part ? l_i : l_r;
      f32x16* acc = part ? accI : accR;
      float vm = s[0];
#pragma unroll
      for (int j = 1; j < 16; ++j) vm = fmaxf(vm, s[j]);
      vm = fmaxf(vm, __shfl_xor(vm, 32));
      if (__any(vm > m + 8.f)) {
        float mn = fmaxf(m, vm);
        float sc = __expf(m - mn);
        lsum *= sc;
#pragma unroll
        for (int a = 0; a < 4; ++a)
#pragma unroll
          for (int j = 0; j < 16; ++j) acc[a][j] *= sc;
        m = mn;
      }
      float p[16];
      float ls = 0.f;
#pragma unroll
      for (int j = 0; j < 16; ++j) { p[j] = __expf(s[j] - m); ls += p[j]; }
      lsum += ls;
      unsigned a0 = pkrtz(p[0], p[1]), b0 = pkrtz(p[4], p[5]);
      unsigned a1 = pkrtz(p[2], p[3]), b1 = pkrtz(p[6], p[7]);
      unsigned a2 = pkrtz(p[8], p[9]), b2 = pkrtz(p[12], p[13]);
      unsigned a3 = pkrtz(p[10], p[11]), b3 = pkrtz(p[14], p[15]);
      asm("v_permlane32_swap_b32 %0, %1" : "+v"(a0), "+v"(b0));
      asm("v_permlane32_swap_b32 %0, %1" : "+v"(a1), "+v"(b1));
      asm("v_permlane32_swap_b32 %0, %1" : "+v"(a2), "+v"(b2));
      asm("v_permlane32_swap_b32 %0, %1" : "+v"(a3), "+v"(b3));
      union { unsigned u[4]; f16x8 v; } f0, f1;
      f0.u[0] = a0; f0.u[1] = a1; f0.u[2] = b0; f0.u[3] = b1;
      f1.u[0] = a2; f1.u[1] = a3; f1.u[2] = b2; f1.u[3] = b3;
      if (part) { pif[0] = f0.v; pif[1] = f1.v; }
      else      { prf[0] = f0.v; prf[1] = f1.v; }
    }

    __builtin_amdgcn_s_setprio(1);
#pragma unroll
    for (int ft = 0; ft < 4; ++ft) {
#pragma unroll
      for (int ks = 0; ks < 2; ++ks) {
        int feat = ft * 32 + lq;
        int prow = feat >> 1;
        int swzc = (((feat & 1) * 4 + ks * 2 + hi) ^ (prow & 7));
        f16x8 vf = *(const f16x8*)&sV[cur][prow * 64 + swzc * 8];
        accR[ft] = MFMA32(vf, prf[ks], accR[ft]);
        accI[ft] = MFMA32(vf, pif[ks], accI[ft]);
      }
    }
    __builtin_amdgcn_s_setprio(0);

    asm volatile("s_waitcnt vmcnt(0)" ::: "memory");
    __syncthreads();
    cur ^= 1;
  }
#undef STAGE

  float lr = l_r + __shfl_xor(l_r, 32);
  float li = l_i + __shfl_xor(l_i, 32);
  float ilr = 1.f / lr, ili = 1.f / li;
  const int bb = bh >> 4, h = bh & 15;
  const int q = q0 + lq;
  f16* rowp = OC + ((size_t)bb * 1024 + q) * 2048 + h * 64;
#pragma unroll
  for (int tt = 0; tt < 2; ++tt) {
#pragma unroll
    for (int g = 0; g < 4; ++g) {
      int d0 = tt * 32 + g * 8 + hi * 4;
      f16x4 ov, oiv;
#pragma unroll
      for (int j = 0; j < 4; ++j) {
        int rg = g * 4 + j;
        float orv = accR[tt][rg] * ilr - accI[tt + 2][rg] * ili;
        float oivv = accR[tt + 2][rg] * ilr + accI[tt][rg] * ili;
        ov[j] = (f16)orv;
        oiv[j] = (f16)oivv;
      }
      *(f16x4*)(rowp + d0) = ov;
      *(f16x4*)(rowp + 1024 + d0) = oiv;
    }
  }
}

// ---------------- launcher ----------------------------------------------------

extern "C" void kernel_launch(void* const* d_in, const int* in_sizes, int n_in,
                              void* d_out, int out_size, void* d_ws, size_t ws_size,
                              hipStream_t stream) {
  const float* xr = (const float*)d_in[0];
  const float* xi = (const float*)d_in[1];
  const float* wpr = (const float*)d_in[2];
  const float* wpi = (const float*)d_in[3];
  const float* bpr = (const float*)d_in[4];
  const float* bpi = (const float*)d_in[5];
  const float* wor = (const float*)d_in[6];
  const float* woi = (const float*)d_in[7];
  const float* bor = (const float*)d_in[8];
  const float* boi = (const float*)d_in[9];

  f16* ws = (f16*)d_ws;
  f16* XC = ws;                       // 4096*2048
  f16* WQKV = XC + 8388608;           // 6144*2048
  f16* QC = WQKV + 12582912;          // 64*1024*128
  f16* KCr = QC + 8388608;
  f16* KCi = KCr + 8388608;
  f16* VCT = KCi + 8388608;           // 64*128*1024
  f16* OC = VCT + 8388608;            // 4096*2048
  f16* WOUT = OC + 8388608;           // 2048*2048

  pack_x_kernel<<<8192, 256, 0, stream>>>(xr, xi, XC);
  pack_wqkv_kernel<<<12288, 256, 0, stream>>>(wpr, wpi, WQKV);
  pack_wout_kernel<<<4096, 256, 0, stream>>>(wor, woi, WOUT);

  GemmParams p1 = {};
  p1.QC = QC; p1.KCr = KCr; p1.KCi = KCi; p1.VCT = VCT;
  p1.bpr = bpr; p1.bpi = bpi;
  // 8 XCD x (32 m-tiles x 6 n-tiles) = 1536 blocks
  gemm_kernel<0><<<1536, 256, 0, stream>>>(XC, WQKV, p1, 6);

  attn_kernel<<<256, 512, 0, stream>>>(QC, KCr, KCi, VCT, OC);

  GemmParams p2 = {};
  p2.out = (float*)d_out; p2.bor = bor; p2.boi = boi;
  p2.out_complex = (out_size == 8388608) ? 1 : 0;
  int ntPer = p2.out_complex ? 2 : 1;  // N = 2048 or 1024
  gemm_kernel<1><<<8 * 32 * ntPer, 256, 0, stream>>>(OC, WOUT, p2, ntPer);
}